// Round 9
// baseline (395.059 us; speedup 1.0000x reference)
//
#include <hip/hip_runtime.h>
#include <stdint.h>

#define M_DIM 16384
#define K_DIM 1024
#define N_DIM 4096
#define BM 128
#define BN 128
#define LDSP 40          // fallback-path pad

#define TILE_ELEMS (128 * K_DIM)      // 131072 bf16 per 128-row packed tile
#define SLAB_ELEMS (128 * 32)         // 4096 bf16 per (tile, s) slab
#define NSLAB_X ((M_DIM / 128) * 32)  // 4096
#define NSLAB_W ((N_DIM / 128) * 32)  // 1024
#define CROW 20                        // convert LDS row stride (dwords)

typedef __bf16 bf16;
typedef __attribute__((ext_vector_type(8))) __bf16 bf16x8;
typedef __attribute__((ext_vector_type(4))) float f32x4;

// round-to-nearest-even fp32 -> bf16, packed two at a time (no NaN inputs)
__device__ __forceinline__ uint32_t pack2_bf16(float a, float b) {
    uint32_t ua = __float_as_uint(a);
    uint32_t ub = __float_as_uint(b);
    ua += 0x7fffu + ((ua >> 16) & 1u);
    ub += 0x7fffu + ((ub >> 16) & 1u);
    return (ua >> 16) | (ub & 0xffff0000u);
}

// ---- convert fp32 -> bf16 and repack into MFMA-fragment order --------------
// Packed layout per 128-row tile: [s:32][rb:8][lane:64][j:8], lane = q*16+lrow,
// src row = rb*16 + lrow, src col = s*32 + q*8 + j.
// Also zeroes d_out (poisoned 0xAA before every call) -> no memset dispatch.
__global__ __launch_bounds__(256) void convert_pack_kernel(
    const float* __restrict__ x, const float* __restrict__ w,
    bf16* __restrict__ xp, bf16* __restrict__ wp, float* __restrict__ out)
{
    int slab = blockIdx.x;
    const int t = threadIdx.x;
    if (slab < (M_DIM / 256)) out[slab * 256 + t] = 0.f;   // 64 blocks zero out[]

    const float* src;
    bf16* dst;
    if (slab < NSLAB_X) { src = x; dst = xp; }
    else                { slab -= NSLAB_X; src = w; dst = wp; }
    const int tile = slab >> 5;
    const int s    = slab & 31;

    __shared__ uint32_t ls[128 * CROW];   // 10 KB

    // phase 1: coalesced read of 16 fp32, convert, store to LDS row-major
    {
        const int r  = t >> 1;            // 0..127
        const int kh = (t & 1) * 16;      // fp32 col offset within slab
        const float4* p = (const float4*)(src + (size_t)(tile * 128 + r) * K_DIM + s * 32 + kh);
        float4 a = p[0], b = p[1], c = p[2], d = p[3];
        uint4* lp = (uint4*)&ls[r * CROW + (t & 1) * 8];
        uint4 v0, v1;
        v0.x = pack2_bf16(a.x, a.y); v0.y = pack2_bf16(a.z, a.w);
        v0.z = pack2_bf16(b.x, b.y); v0.w = pack2_bf16(b.z, b.w);
        v1.x = pack2_bf16(c.x, c.y); v1.y = pack2_bf16(c.z, c.w);
        v1.z = pack2_bf16(d.x, d.y); v1.w = pack2_bf16(d.z, d.w);
        lp[0] = v0; lp[1] = v1;
    }
    __syncthreads();
    // phase 2: emit 512 fragment chunks (16 B each), coalesced store
    uint4* dst4 = (uint4*)(dst + (size_t)tile * TILE_ELEMS + (size_t)s * SLAB_ELEMS);
    #pragma unroll
    for (int p = 0; p < 2; ++p) {
        const int c    = t + p * 256;     // chunk 0..511
        const int lane = c & 63;
        const int rb   = c >> 6;
        const int q    = lane >> 4;
        const int lrow = lane & 15;
        const int r    = rb * 16 + lrow;
        const uint4* lp = (const uint4*)&ls[r * CROW + q * 4];
        dst4[c] = lp[0];
    }
}

// ---- direct-from-global MFMA GEMM, 128x64 wave tile (high intensity) -------
// Demand model (R8 post-mortem): vector-load path caps at ~40 B/cyc/CU.
// FLOP per demanded byte: 64x64 tile = 32, 128x64 = 42.7 -> demand 4.29->3.22 GB.
__device__ __forceinline__ void load8(const bf16* base, uint32_t off, bf16x8* f) {
    #pragma unroll
    for (int i = 0; i < 8; ++i) f[i] = *(const bf16x8*)(base + off + i * 512);
}
__device__ __forceinline__ void load4(const bf16* base, uint32_t off, bf16x8* f) {
    #pragma unroll
    for (int j = 0; j < 4; ++j) f[j] = *(const bf16x8*)(base + off + j * 512);
}

__device__ __forceinline__ void mfma84(const bf16x8* af, const bf16x8* bf,
                                       f32x4 acc[8][4]) {
    #pragma unroll
    for (int i = 0; i < 8; ++i)
        #pragma unroll
        for (int j = 0; j < 4; ++j)
            acc[i][j] = __builtin_amdgcn_mfma_f32_16x16x32_bf16(af[i], bf[j], acc[i][j], 0, 0, 0);
}

// 2 waves/SIMD (256-reg budget): acc 128 AGPR + frag dbuf ~96 VGPR + misc fits.
__global__ __launch_bounds__(256, 2) void gemm_pool_direct_kernel(
    const bf16* __restrict__ xp, const bf16* __restrict__ wp,
    const float* __restrict__ bias, float* __restrict__ out)
{
    // XCD stripe map over 2048 blocks: per XCD per phase, A stripe = 4 M-tiles
    // of 256 rows (2 MB); bx sweeps so active B tiles stay L2/L3-hot.
    const int b     = blockIdx.x;
    const int xcd   = b & 7;
    const int o     = (b >> 3) & 3;
    const int bx    = (b >> 5) & 31;
    const int phase = (b >> 10) & 1;
    const int mt    = phase * 32 + xcd * 4 + o;   // 256-row M tile, 0..63

    const int lane = threadIdx.x & 63;
    const int wave = threadIdx.x >> 6;
    const int wm = wave >> 1;    // which packed 128-row A tile of the pair
    const int wn = wave & 1;     // N half (64 cols)
    const int lr = lane & 15;
    const int quad = lane >> 4;

    const bf16* Ab = xp + (size_t)(2 * mt + wm) * TILE_ELEMS;  // SGPR base
    const bf16* Bb = wp + (size_t)bx * TILE_ELEMS;             // SGPR base
    const uint32_t aoff = lane * 8;                  // rb folds into imm offset
    const uint32_t boff = (wn * 4) * 512 + lane * 8;

    f32x4 acc[8][4] = {};
    bf16x8 aA[8], bA[4], aB[8], bB[4];

    // 1-ahead register double buffer; no barriers -> fine-grained vmcnt waits.
    load8(Ab, aoff, aA);
    load4(Bb, boff, bA);
    #pragma unroll
    for (int s = 0; s < 32; s += 2) {
        load8(Ab, aoff + (s + 1) * SLAB_ELEMS, aB);
        load4(Bb, boff + (s + 1) * SLAB_ELEMS, bB);
        mfma84(aA, bA, acc);
        if (s + 2 < 32) {
            load8(Ab, aoff + (s + 2) * SLAB_ELEMS, aA);
            load4(Bb, boff + (s + 2) * SLAB_ELEMS, bA);
        }
        mfma84(aB, bB, acc);
    }

    // fused epilogue: +bias, maxpool4 along N, row-sum, atomic out
    // C/D layout: col = lane&15, row = quad*4 + reg  [m89/m91]
    float bv[4];
    #pragma unroll
    for (int j = 0; j < 4; ++j)
        bv[j] = bias[bx * BN + wn * 64 + j * 16 + lr];

    const int rowbase = (2 * mt + wm) * 128;
    #pragma unroll
    for (int i = 0; i < 8; ++i) {
        float rs[4] = {0.f, 0.f, 0.f, 0.f};
        #pragma unroll
        for (int j = 0; j < 4; ++j) {
            #pragma unroll
            for (int r = 0; r < 4; ++r) {
                float t = acc[i][j][r] + bv[j];
                t = fmaxf(t, __shfl_xor(t, 1, 64));   // quad_perm DPP
                t = fmaxf(t, __shfl_xor(t, 2, 64));
                rs[r] += t;    // all 4 lanes of a pool group hold the max
            }
        }
        #pragma unroll
        for (int r = 0; r < 4; ++r) {
            rs[r] += __shfl_xor(rs[r], 4, 64);
            rs[r] += __shfl_xor(rs[r], 8, 64);
        }
        if (lr == 0) {
            const int row = rowbase + i * 16 + quad * 4;
            #pragma unroll
            for (int r = 0; r < 4; ++r)
                atomicAdd(&out[row + r], rs[r] * 0.5f);
        }
    }
}

// ---- fallback (round-1 kernel) if ws too small -----------------------------
__global__ __launch_bounds__(256) void fused_linear_pool_kernel(
    const float* __restrict__ x, const float* __restrict__ wt,
    const float* __restrict__ bias, float* __restrict__ out)
{
    __shared__ uint32_t sA[BM * LDSP / 2];
    __shared__ uint32_t sB[BN * LDSP / 2];

    const int tid = threadIdx.x;
    const int bx = blockIdx.x;
    const int by = blockIdx.y;

    const float* Abase = x  + (size_t)by * BM * K_DIM;
    const float* Bbase = wt + (size_t)bx * BN * K_DIM;

    const int lane = tid & 63;
    const int wave = tid >> 6;
    const int wm = wave >> 1;
    const int wn = wave & 1;
    const int lr = lane & 15;
    const int quad = lane >> 4;

    const int srow  = tid >> 2;
    const int scol  = (tid & 3) * 8;
    const int swidx = (tid & 3) * 4;

    f32x4 acc[4][4] = {};

    for (int kt = 0; kt < K_DIM; kt += 32) {
        #pragma unroll
        for (int p = 0; p < 2; ++p) {
            const int r = srow + p * 64;
            const float4* ga = (const float4*)(Abase + (size_t)r * K_DIM + kt + scol);
            const float4* gb = (const float4*)(Bbase + (size_t)r * K_DIM + kt + scol);
            float4 a0 = ga[0], a1 = ga[1], b0 = gb[0], b1 = gb[1];
            uint4 wa;
            wa.x = pack2_bf16(a0.x, a0.y); wa.y = pack2_bf16(a0.z, a0.w);
            wa.z = pack2_bf16(a1.x, a1.y); wa.w = pack2_bf16(a1.z, a1.w);
            *(uint4*)&sA[r * (LDSP / 2) + swidx] = wa;
            uint4 wbv;
            wbv.x = pack2_bf16(b0.x, b0.y); wbv.y = pack2_bf16(b0.z, b0.w);
            wbv.z = pack2_bf16(b1.x, b1.y); wbv.w = pack2_bf16(b1.z, b1.w);
            *(uint4*)&sB[r * (LDSP / 2) + swidx] = wbv;
        }
        __syncthreads();

        bf16x8 af[4], bfr[4];
        #pragma unroll
        for (int i = 0; i < 4; ++i)
            af[i] = *(const bf16x8*)((const bf16*)sA + (wm * 64 + i * 16 + lr) * LDSP + quad * 8);
        #pragma unroll
        for (int j = 0; j < 4; ++j)
            bfr[j] = *(const bf16x8*)((const bf16*)sB + (wn * 64 + j * 16 + lr) * LDSP + quad * 8);

        #pragma unroll
        for (int i = 0; i < 4; ++i)
            #pragma unroll
            for (int j = 0; j < 4; ++j)
                acc[i][j] = __builtin_amdgcn_mfma_f32_16x16x32_bf16(af[i], bfr[j], acc[i][j], 0, 0, 0);
        __syncthreads();
    }

    float bv[4];
    #pragma unroll
    for (int j = 0; j < 4; ++j)
        bv[j] = bias[bx * BN + wn * 64 + j * 16 + lr];

    #pragma unroll
    for (int i = 0; i < 4; ++i) {
        float rsum[4] = {0.f, 0.f, 0.f, 0.f};
        #pragma unroll
        for (int j = 0; j < 4; ++j) {
            #pragma unroll
            for (int r = 0; r < 4; ++r) {
                float t = acc[i][j][r] + bv[j];
                t = fmaxf(t, __shfl_xor(t, 1, 64));
                t = fmaxf(t, __shfl_xor(t, 2, 64));
                t += __shfl_xor(t, 4, 64);
                t += __shfl_xor(t, 8, 64);
                rsum[r] += t;
            }
        }
        if (lr == 0) {
            const int row = by * BM + wm * 64 + i * 16 + quad * 4;
            #pragma unroll
            for (int r = 0; r < 4; ++r)
                atomicAdd(&out[row + r], rsum[r] * 0.5f);
        }
    }
}

extern "C" void kernel_launch(void* const* d_in, const int* in_sizes, int n_in,
                              void* d_out, int out_size, void* d_ws, size_t ws_size,
                              hipStream_t stream) {
    const float* x  = (const float*)d_in[0];
    const float* wt = (const float*)d_in[1];
    const float* bs = (const float*)d_in[2];
    float* out = (float*)d_out;

    const size_t xe = (size_t)M_DIM * K_DIM;
    const size_t we = (size_t)N_DIM * K_DIM;
    const size_t need = (xe + we) * sizeof(bf16);  // ~42 MB

    if (ws_size >= need) {
        bf16* xp = (bf16*)d_ws;
        bf16* wp = xp + xe;
        convert_pack_kernel<<<NSLAB_X + NSLAB_W, 256, 0, stream>>>(x, wt, xp, wp, out);
        gemm_pool_direct_kernel<<<(M_DIM / 256) * (N_DIM / BN), 256, 0, stream>>>(xp, wp, bs, out);
    } else {
        hipMemsetAsync(out, 0, (size_t)out_size * sizeof(float), stream);
        dim3 grid(N_DIM / BN, M_DIM / BM);
        fused_linear_pool_kernel<<<grid, 256, 0, stream>>>(x, wt, bs, out);
    }
}

// Round 10
// 262.932 us; speedup vs baseline: 1.5025x; 1.5025x over previous
//
#include <hip/hip_runtime.h>
#include <stdint.h>

#define M_DIM 16384
#define K_DIM 1024
#define N_DIM 4096
#define BM 128
#define BN 128
#define LDSP 40          // fallback-path pad

#define TILE_ELEMS (128 * K_DIM)      // 131072 bf16 per 128-row packed tile
#define SLAB_ELEMS (128 * 32)         // 4096 bf16 per (tile, s) slab
#define CPAD 516                       // convert LDS row stride (dwords), b128-aligned

typedef __bf16 bf16;
typedef __attribute__((ext_vector_type(8))) __bf16 bf16x8;
typedef __attribute__((ext_vector_type(4))) float f32x4;

// round-to-nearest-even fp32 -> bf16, packed two at a time (no NaN inputs)
__device__ __forceinline__ uint32_t pack2_bf16(float a, float b) {
    uint32_t ua = __float_as_uint(a);
    uint32_t ub = __float_as_uint(b);
    ua += 0x7fffu + ((ua >> 16) & 1u);
    ub += 0x7fffu + ((ub >> 16) & 1u);
    return (ua >> 16) | (ub & 0xffff0000u);
}

// ---- convert fp32 -> bf16 + repack into MFMA-fragment order, v2 ------------
// Packed layout per 128-row tile: [s:32][rb:8][lane:64][j:8], lane = q*16+lrow,
// src row = rb*16 + lrow, src col = s*32 + q*8 + j.
// v2: block = 16 full source rows (64 KB fp32). Phase-1 instr i reads row i
// fully contiguously (1 KB per wave-instr, no address divergence — R9's
// convert read 32 lines 4 KB apart per instr). Phase-2 stores are 1 KB
// contiguous per instr. Also zeroes d_out (poisoned 0xAA before every call).
__global__ __launch_bounds__(256) void convert_pack_kernel(
    const float* __restrict__ x, const float* __restrict__ w,
    bf16* __restrict__ xp, bf16* __restrict__ wp, float* __restrict__ out)
{
    int g = blockIdx.x;
    const int t = threadIdx.x;
    if (g < (M_DIM / 256)) out[g * 256 + t] = 0.f;   // 64 blocks zero out[]

    const float* src;
    bf16* dst;
    if (g < (M_DIM / 16)) {
        src = x + (size_t)g * 16 * K_DIM;  dst = xp;
    } else {
        g -= M_DIM / 16;
        src = w + (size_t)g * 16 * K_DIM;  dst = wp;
    }
    const int tile = g >> 3;
    const int rb   = g & 7;

    __shared__ uint32_t ls[16 * CPAD];   // ~33 KB

    // phase 1: 16 coalesced row reads -> pack -> LDS row-major
    #pragma unroll
    for (int i = 0; i < 16; ++i) {
        float4 v = ((const float4*)src)[i * 256 + t];   // row i, cols 4t..4t+3
        uint2 d;
        d.x = pack2_bf16(v.x, v.y);
        d.y = pack2_bf16(v.z, v.w);
        *(uint2*)&ls[i * CPAD + t * 2] = d;
    }
    __syncthreads();

    // phase 2: wave wv emits s = wv, wv+4, ... ; 1 KB contiguous per instr
    const int wv = t >> 6, l = t & 63;
    const int lrow = l & 15, q = l >> 4;
    uint4* dst4 = (uint4*)(dst + (size_t)tile * TILE_ELEMS);
    #pragma unroll
    for (int it = 0; it < 8; ++it) {
        const int s = wv + it * 4;
        uint4 v = *(const uint4*)&ls[lrow * CPAD + s * 16 + q * 4];
        dst4[(s * 8 + rb) * 64 + l] = v;
    }
}

// ---- direct-from-global MFMA GEMM (R8 verbatim — the measured fixed point) -
__device__ __forceinline__ void load_set(const bf16* base, uint32_t off, bf16x8* f) {
    #pragma unroll
    for (int i = 0; i < 4; ++i) f[i] = *(const bf16x8*)(base + off + i * 512);
}

__device__ __forceinline__ void do_mfma(const bf16x8* af, const bf16x8* bf,
                                        f32x4 acc[4][4]) {
    #pragma unroll
    for (int i = 0; i < 4; ++i)
        #pragma unroll
        for (int j = 0; j < 4; ++j)
            acc[i][j] = __builtin_amdgcn_mfma_f32_16x16x32_bf16(af[i], bf[j], acc[i][j], 0, 0, 0);
}

__global__ __launch_bounds__(256, 2) void gemm_pool_direct_kernel(
    const bf16* __restrict__ xp, const bf16* __restrict__ wp,
    const float* __restrict__ bias, float* __restrict__ out)
{
    // 2-phase XCD stripe map: per XCD per phase, A stripe = 8 tiles (2 MB);
    // bx sweeps slowly so the active B tiles stay L2/L3-hot.
    const int b     = blockIdx.x;
    const int xcd   = b & 7;
    const int o     = (b >> 3) & 7;
    const int bx    = (b >> 6) & 31;
    const int phase = b >> 11;
    const int by    = phase * 64 + xcd * 8 + o;

    const int lane = threadIdx.x & 63;
    const int wave = threadIdx.x >> 6;
    const int wm = wave >> 1;
    const int wn = wave & 1;
    const int lr = lane & 15;
    const int quad = lane >> 4;

    const bf16* Ab = xp + (size_t)by * TILE_ELEMS;   // SGPR base
    const bf16* Bb = wp + (size_t)bx * TILE_ELEMS;   // SGPR base
    const uint32_t aoff = (wm * 4) * 512 + lane * 8;
    const uint32_t boff = (wn * 4) * 512 + lane * 8;

    f32x4 acc[4][4] = {};
    bf16x8 Af[3][4];
    bf16x8 Bf[5][4];

    // prologue
    load_set(Bb, boff + 0 * SLAB_ELEMS, Bf[0]);
    load_set(Bb, boff + 1 * SLAB_ELEMS, Bf[1]);
    load_set(Bb, boff + 2 * SLAB_ELEMS, Bf[2]);
    load_set(Bb, boff + 3 * SLAB_ELEMS, Bf[3]);
    load_set(Ab, aoff + 0 * SLAB_ELEMS, Af[0]);
    load_set(Ab, aoff + 1 * SLAB_ELEMS, Af[1]);

    #pragma unroll
    for (int s = 0; s < 32; ++s) {
        if (s + 4 < 32) load_set(Bb, boff + (s + 4) * SLAB_ELEMS, Bf[(s + 4) % 5]);
        if (s + 2 < 32) load_set(Ab, aoff + (s + 2) * SLAB_ELEMS, Af[(s + 2) % 3]);
        do_mfma(Af[s % 3], Bf[s % 5], acc);
    }

    // fused epilogue: +bias, maxpool4 along N, row-sum, atomic out
    // C/D layout: col = lane&15, row = quad*4 + reg  [m89/m91]
    float bv[4];
    #pragma unroll
    for (int j = 0; j < 4; ++j)
        bv[j] = bias[bx * BN + wn * 64 + j * 16 + lr];

    #pragma unroll
    for (int i = 0; i < 4; ++i) {
        float rs[4] = {0.f, 0.f, 0.f, 0.f};
        #pragma unroll
        for (int j = 0; j < 4; ++j) {
            #pragma unroll
            for (int r = 0; r < 4; ++r) {
                float t = acc[i][j][r] + bv[j];
                t = fmaxf(t, __shfl_xor(t, 1, 64));   // quad_perm DPP
                t = fmaxf(t, __shfl_xor(t, 2, 64));
                rs[r] += t;    // all 4 lanes of a pool group hold the max
            }
        }
        #pragma unroll
        for (int r = 0; r < 4; ++r) {
            rs[r] += __shfl_xor(rs[r], 4, 64);
            rs[r] += __shfl_xor(rs[r], 8, 64);
        }
        if (lr == 0) {
            const int row = by * BM + wm * 64 + i * 16 + quad * 4;
            #pragma unroll
            for (int r = 0; r < 4; ++r)
                atomicAdd(&out[row + r], rs[r] * 0.5f);
        }
    }
}

// ---- fallback (round-1 kernel) if ws too small -----------------------------
__global__ __launch_bounds__(256) void fused_linear_pool_kernel(
    const float* __restrict__ x, const float* __restrict__ wt,
    const float* __restrict__ bias, float* __restrict__ out)
{
    __shared__ uint32_t sA[BM * LDSP / 2];
    __shared__ uint32_t sB[BN * LDSP / 2];

    const int tid = threadIdx.x;
    const int bx = blockIdx.x;
    const int by = blockIdx.y;

    const float* Abase = x  + (size_t)by * BM * K_DIM;
    const float* Bbase = wt + (size_t)bx * BN * K_DIM;

    const int lane = tid & 63;
    const int wave = tid >> 6;
    const int wm = wave >> 1;
    const int wn = wave & 1;
    const int lr = lane & 15;
    const int quad = lane >> 4;

    const int srow  = tid >> 2;
    const int scol  = (tid & 3) * 8;
    const int swidx = (tid & 3) * 4;

    f32x4 acc[4][4] = {};

    for (int kt = 0; kt < K_DIM; kt += 32) {
        #pragma unroll
        for (int p = 0; p < 2; ++p) {
            const int r = srow + p * 64;
            const float4* ga = (const float4*)(Abase + (size_t)r * K_DIM + kt + scol);
            const float4* gb = (const float4*)(Bbase + (size_t)r * K_DIM + kt + scol);
            float4 a0 = ga[0], a1 = ga[1], b0 = gb[0], b1 = gb[1];
            uint4 wa;
            wa.x = pack2_bf16(a0.x, a0.y); wa.y = pack2_bf16(a0.z, a0.w);
            wa.z = pack2_bf16(a1.x, a1.y); wa.w = pack2_bf16(a1.z, a1.w);
            *(uint4*)&sA[r * (LDSP / 2) + swidx] = wa;
            uint4 wbv;
            wbv.x = pack2_bf16(b0.x, b0.y); wbv.y = pack2_bf16(b0.z, b0.w);
            wbv.z = pack2_bf16(b1.x, b1.y); wbv.w = pack2_bf16(b1.z, b1.w);
            *(uint4*)&sB[r * (LDSP / 2) + swidx] = wbv;
        }
        __syncthreads();

        bf16x8 af[4], bfr[4];
        #pragma unroll
        for (int i = 0; i < 4; ++i)
            af[i] = *(const bf16x8*)((const bf16*)sA + (wm * 64 + i * 16 + lr) * LDSP + quad * 8);
        #pragma unroll
        for (int j = 0; j < 4; ++j)
            bfr[j] = *(const bf16x8*)((const bf16*)sB + (wn * 64 + j * 16 + lr) * LDSP + quad * 8);

        #pragma unroll
        for (int i = 0; i < 4; ++i)
            #pragma unroll
            for (int j = 0; j < 4; ++j)
                acc[i][j] = __builtin_amdgcn_mfma_f32_16x16x32_bf16(af[i], bfr[j], acc[i][j], 0, 0, 0);
        __syncthreads();
    }

    float bv[4];
    #pragma unroll
    for (int j = 0; j < 4; ++j)
        bv[j] = bias[bx * BN + wn * 64 + j * 16 + lr];

    #pragma unroll
    for (int i = 0; i < 4; ++i) {
        float rsum[4] = {0.f, 0.f, 0.f, 0.f};
        #pragma unroll
        for (int j = 0; j < 4; ++j) {
            #pragma unroll
            for (int r = 0; r < 4; ++r) {
                float t = acc[i][j][r] + bv[j];
                t = fmaxf(t, __shfl_xor(t, 1, 64));
                t = fmaxf(t, __shfl_xor(t, 2, 64));
                t += __shfl_xor(t, 4, 64);
                t += __shfl_xor(t, 8, 64);
                rsum[r] += t;
            }
        }
        if (lr == 0) {
            const int row = by * BM + wm * 64 + i * 16 + quad * 4;
            #pragma unroll
            for (int r = 0; r < 4; ++r)
                atomicAdd(&out[row + r], rsum[r] * 0.5f);
        }
    }
}

extern "C" void kernel_launch(void* const* d_in, const int* in_sizes, int n_in,
                              void* d_out, int out_size, void* d_ws, size_t ws_size,
                              hipStream_t stream) {
    const float* x  = (const float*)d_in[0];
    const float* wt = (const float*)d_in[1];
    const float* bs = (const float*)d_in[2];
    float* out = (float*)d_out;

    const size_t xe = (size_t)M_DIM * K_DIM;
    const size_t we = (size_t)N_DIM * K_DIM;
    const size_t need = (xe + we) * sizeof(bf16);  // ~42 MB

    if (ws_size >= need) {
        bf16* xp = (bf16*)d_ws;
        bf16* wp = xp + xe;
        const int nconv = (M_DIM / 16) + (N_DIM / 16);   // 1024 + 256 = 1280
        convert_pack_kernel<<<nconv, 256, 0, stream>>>(x, wt, xp, wp, out);
        gemm_pool_direct_kernel<<<(M_DIM / BM) * (N_DIM / BN), 256, 0, stream>>>(xp, wp, bs, out);
    } else {
        hipMemsetAsync(out, 0, (size_t)out_size * sizeof(float), stream);
        dim3 grid(N_DIM / BN, M_DIM / BM);
        fused_linear_pool_kernel<<<grid, 256, 0, stream>>>(x, wt, bs, out);
    }
}